// Round 1
// baseline (3598.783 us; speedup 1.0000x reference)
//
#include <hip/hip_runtime.h>
#include <math.h>

// CTRNN + adaptive DOPRI5 (B=2048, N=1024, 40-step static budget).
// Round 1: fp32-exact scaffold. y state lives in d_out. Scalars + stage
// arrays in d_ws (needs 256 + 9*8MB ~= 72MB).

typedef float f4 __attribute__((ext_vector_type(4)));

#define BB 2048
#define NN 1024
#define TOT (BB * NN)
#define NV (TOT / 4)            // float4 elements
#define COLMASK (NN / 4 - 1)    // 255

// DOPRI5 error coefficients (b5-b4)
#define E1c (71.0f / 57600.0f)
#define E3c (-71.0f / 16695.0f)
#define E4c (71.0f / 1920.0f)
#define E5c (-17253.0f / 339200.0f)
#define E6c (22.0f / 525.0f)
#define E7c (-1.0f / 40.0f)

struct Ctl {
  double sum;      // error-norm accumulator
  float t, dt, h;
  int done, step_ok;
};

__global__ void k_init(const f4* __restrict__ prev, f4* __restrict__ y, Ctl* c) {
  int i = blockIdx.x * blockDim.x + threadIdx.x;
  y[i] = prev[i];
  if (blockIdx.x == 0 && threadIdx.x == 0) {
    c->t = 0.0f; c->dt = 0.1f; c->h = 0.0f; c->done = 0; c->step_ok = 0; c->sum = 0.0;
  }
}

__global__ void k_begin(Ctl* c) {
  float t = c->t;
  int done = (t >= 1.0f - 1e-7f) ? 1 : 0;
  c->done = done;
  c->h = done ? 0.0f : fminf(c->dt, 1.0f - t);
  c->sum = 0.0;
  c->step_ok = 0;
}

// act = tanh(y + bias)   (stage 1 input)
__global__ void k_act1(const Ctl* __restrict__ c, const f4* __restrict__ y,
                       const f4* __restrict__ bias, f4* __restrict__ act) {
  if (c->done) return;
  int i = blockIdx.x * blockDim.x + threadIdx.x;
  f4 v = y[i];
  f4 b = bias[i & COLMASK];
  f4 a;
#pragma unroll
  for (int j = 0; j < 4; ++j) a[j] = tanhf(v[j] + b[j]);
  act[i] = a;
}

// rec[b,i] = sum_j act[b,j] * W[i,j]   (C = A * W^T, both row-major, K contiguous)
#define BM 64
#define BN 64
#define BK 16
#define PADW 68

__global__ __launch_bounds__(256) void k_gemm(const Ctl* __restrict__ c,
                                              const float* __restrict__ A,
                                              const float* __restrict__ W,
                                              float* __restrict__ C) {
  if (c->done) return;
  __shared__ float As[BK][PADW];
  __shared__ float Bs[BK][PADW];
  int tid = (int)threadIdx.x;
  int kk = tid & 15, mm = tid >> 4;   // load indices
  int tx = tid & 15, ty = tid >> 4;   // compute indices
  int rowBase = blockIdx.x * BM, colBase = blockIdx.y * BN;
  float acc[4][4] = {};
  for (int k0 = 0; k0 < NN; k0 += BK) {
    __syncthreads();
#pragma unroll
    for (int r = 0; r < 4; ++r) {
      As[kk][mm + 16 * r] = A[(size_t)(rowBase + mm + 16 * r) * NN + k0 + kk];
      Bs[kk][mm + 16 * r] = W[(size_t)(colBase + mm + 16 * r) * NN + k0 + kk];
    }
    __syncthreads();
#pragma unroll
    for (int k = 0; k < BK; ++k) {
      float a0 = As[k][ty * 4 + 0], a1 = As[k][ty * 4 + 1];
      float a2 = As[k][ty * 4 + 2], a3 = As[k][ty * 4 + 3];
      float b0 = Bs[k][tx * 4 + 0], b1 = Bs[k][tx * 4 + 1];
      float b2 = Bs[k][tx * 4 + 2], b3 = Bs[k][tx * 4 + 3];
      acc[0][0] += a0 * b0; acc[0][1] += a0 * b1; acc[0][2] += a0 * b2; acc[0][3] += a0 * b3;
      acc[1][0] += a1 * b0; acc[1][1] += a1 * b1; acc[1][2] += a1 * b2; acc[1][3] += a1 * b3;
      acc[2][0] += a2 * b0; acc[2][1] += a2 * b1; acc[2][2] += a2 * b2; acc[2][3] += a2 * b3;
      acc[3][0] += a3 * b0; acc[3][1] += a3 * b1; acc[3][2] += a3 * b2; acc[3][3] += a3 * b3;
    }
  }
  int row0 = rowBase + ty * 4, col0 = colBase + tx * 4;
#pragma unroll
  for (int r = 0; r < 4; ++r) {
    f4 v; v[0] = acc[r][0]; v[1] = acc[r][1]; v[2] = acc[r][2]; v[3] = acc[r][3];
    *(f4*)&C[(size_t)(row0 + r) * NN + col0] = v;
  }
}

// After GEMM of stage S: k_S = inv_tau*(-ys_S + rec + drive); then build
// ys_{S+1} and act_{S+1}. kb holds k1..k6 at stride NV (f4 units).
template <int S>
__global__ void k_fuse(const Ctl* __restrict__ c,
                       const f4* __restrict__ y, f4* __restrict__ ys,
                       const f4* __restrict__ rec, f4* __restrict__ act,
                       f4* __restrict__ kb,
                       const f4* __restrict__ inp, const f4* __restrict__ iw,
                       const f4* __restrict__ tau, const f4* __restrict__ bias) {
  if (c->done) return;
  const float h = c->h;
  int i = blockIdx.x * blockDim.x + threadIdx.x;
  int cm = i & COLMASK;
  f4 yv = y[i];
  f4 ysv;
  if (S == 1) ysv = yv; else ysv = ys[i];
  f4 rv = rec[i];
  f4 dv = inp[i] * iw[cm];
  f4 tv = tau[cm];
  f4 bv = bias[cm];
  f4 ks;
#pragma unroll
  for (int j = 0; j < 4; ++j) ks[j] = (1.0f / tv[j]) * (-ysv[j] + rv[j] + dv[j]);
  kb[(size_t)(S - 1) * NV + i] = ks;
  f4 nys;
  if constexpr (S == 1) {
    nys = yv + h * (0.2f * ks);
  } else if constexpr (S == 2) {
    f4 k1 = kb[i];
    nys = yv + h * ((3.0f / 40.0f) * k1 + (9.0f / 40.0f) * ks);
  } else if constexpr (S == 3) {
    f4 k1 = kb[i], k2 = kb[NV + (size_t)i];
    nys = yv + h * ((44.0f / 45.0f) * k1 + (-56.0f / 15.0f) * k2 + (32.0f / 9.0f) * ks);
  } else if constexpr (S == 4) {
    f4 k1 = kb[i], k2 = kb[NV + (size_t)i], k3 = kb[2 * (size_t)NV + i];
    nys = yv + h * ((19372.0f / 6561.0f) * k1 + (-25360.0f / 2187.0f) * k2 +
                    (64448.0f / 6561.0f) * k3 + (-212.0f / 729.0f) * ks);
  } else if constexpr (S == 5) {
    f4 k1 = kb[i], k2 = kb[NV + (size_t)i], k3 = kb[2 * (size_t)NV + i], k4 = kb[3 * (size_t)NV + i];
    nys = yv + h * ((9017.0f / 3168.0f) * k1 + (-355.0f / 33.0f) * k2 +
                    (46732.0f / 5247.0f) * k3 + (49.0f / 176.0f) * k4 +
                    (-5103.0f / 18656.0f) * ks);
  } else {  // S == 6 -> ys becomes y5
    f4 k1 = kb[i], k3 = kb[2 * (size_t)NV + i], k4 = kb[3 * (size_t)NV + i], k5 = kb[4 * (size_t)NV + i];
    nys = yv + h * ((35.0f / 384.0f) * k1 + (500.0f / 1113.0f) * k3 +
                    (125.0f / 192.0f) * k4 + (-2187.0f / 6784.0f) * k5 +
                    (11.0f / 84.0f) * ks);
  }
  ys[i] = nys;
  f4 a;
#pragma unroll
  for (int j = 0; j < 4; ++j) a[j] = tanhf(nys[j] + bv[j]);
  act[i] = a;
}

// Stage 7: k7 in-register, error norm partial sums -> c->sum
__global__ void k_err(Ctl* __restrict__ c,
                      const f4* __restrict__ y, const f4* __restrict__ ys /*y5*/,
                      const f4* __restrict__ rec, const f4* __restrict__ kb,
                      const f4* __restrict__ inp, const f4* __restrict__ iw,
                      const f4* __restrict__ tau) {
  if (c->done) return;
  const float h = c->h;
  int i = blockIdx.x * blockDim.x + threadIdx.x;
  int cm = i & COLMASK;
  f4 yv = y[i], y5 = ys[i], rv = rec[i];
  f4 dv = inp[i] * iw[cm];
  f4 tv = tau[cm];
  f4 k1 = kb[i], k3 = kb[2 * (size_t)NV + i], k4 = kb[3 * (size_t)NV + i];
  f4 k5 = kb[4 * (size_t)NV + i], k6 = kb[5 * (size_t)NV + i];
  float local = 0.0f;
#pragma unroll
  for (int j = 0; j < 4; ++j) {
    float k7 = (1.0f / tv[j]) * (-y5[j] + rv[j] + dv[j]);
    float err = h * (E1c * k1[j] + E3c * k3[j] + E4c * k4[j] + E5c * k5[j] +
                     E6c * k6[j] + E7c * k7);
    float sc = 1e-6f + 1e-3f * fmaxf(fabsf(yv[j]), fabsf(y5[j]));
    float r = err / sc;
    local += r * r;
  }
#pragma unroll
  for (int off = 32; off > 0; off >>= 1) local += __shfl_down(local, off, 64);
  __shared__ float wsum[4];
  int lane = (int)threadIdx.x & 63, wv = (int)threadIdx.x >> 6;
  if (lane == 0) wsum[wv] = local;
  __syncthreads();
  if (threadIdx.x == 0) {
    float s = wsum[0] + wsum[1] + wsum[2] + wsum[3];
    atomicAdd(&c->sum, (double)s);
  }
}

__global__ void k_ctrl(Ctl* c) {
  if (c->done) return;
  float enorm = sqrtf((float)(c->sum * (1.0 / (double)TOT)));
  enorm = fmaxf(enorm, 1e-10f);
  int accept = (enorm <= 1.0f) ? 1 : 0;
  c->step_ok = accept;
  if (accept) c->t = c->t + c->h;
  float factor = 0.9f * powf(enorm, -0.2f);
  factor = fminf(fmaxf(factor, 0.2f), 5.0f);
  c->dt = c->dt * factor;
}

__global__ void k_yupd(const Ctl* __restrict__ c, f4* __restrict__ y,
                       const f4* __restrict__ ys) {
  if (!c->step_ok) return;
  int i = blockIdx.x * blockDim.x + threadIdx.x;
  y[i] = ys[i];
}

extern "C" void kernel_launch(void* const* d_in, const int* in_sizes, int n_in,
                              void* d_out, int out_size, void* d_ws, size_t ws_size,
                              hipStream_t stream) {
  const f4* inputs = (const f4*)d_in[0];
  const f4* prev   = (const f4*)d_in[1];
  const f4* tau    = (const f4*)d_in[2];
  const float* W   = (const float*)d_in[3];
  const f4* iw     = (const f4*)d_in[4];
  const f4* bias   = (const f4*)d_in[5];
  f4* y = (f4*)d_out;

  char* ws = (char*)d_ws;
  Ctl* c = (Ctl*)ws;
  const size_t SZ = (size_t)TOT * sizeof(float);
  f4* ys  = (f4*)(ws + 256);
  float* rec = (float*)(ws + 256 + SZ);
  f4* act = (f4*)(ws + 256 + 2 * SZ);
  f4* kb  = (f4*)(ws + 256 + 3 * SZ);   // k1..k6, stride NV f4s

  dim3 eg(NV / 256), eb(256);
  dim3 gg(BB / BM, NN / BN), gb(256);

  k_init<<<eg, eb, 0, stream>>>(prev, y, c);
  for (int s = 0; s < 40; ++s) {
    k_begin<<<1, 1, 0, stream>>>(c);
    k_act1<<<eg, eb, 0, stream>>>(c, (const f4*)y, bias, act);
    k_gemm<<<gg, gb, 0, stream>>>(c, (const float*)act, W, rec);
    k_fuse<1><<<eg, eb, 0, stream>>>(c, (const f4*)y, ys, (const f4*)rec, act, kb, inputs, iw, tau, bias);
    k_gemm<<<gg, gb, 0, stream>>>(c, (const float*)act, W, rec);
    k_fuse<2><<<eg, eb, 0, stream>>>(c, (const f4*)y, ys, (const f4*)rec, act, kb, inputs, iw, tau, bias);
    k_gemm<<<gg, gb, 0, stream>>>(c, (const float*)act, W, rec);
    k_fuse<3><<<eg, eb, 0, stream>>>(c, (const f4*)y, ys, (const f4*)rec, act, kb, inputs, iw, tau, bias);
    k_gemm<<<gg, gb, 0, stream>>>(c, (const float*)act, W, rec);
    k_fuse<4><<<eg, eb, 0, stream>>>(c, (const f4*)y, ys, (const f4*)rec, act, kb, inputs, iw, tau, bias);
    k_gemm<<<gg, gb, 0, stream>>>(c, (const float*)act, W, rec);
    k_fuse<5><<<eg, eb, 0, stream>>>(c, (const f4*)y, ys, (const f4*)rec, act, kb, inputs, iw, tau, bias);
    k_gemm<<<gg, gb, 0, stream>>>(c, (const float*)act, W, rec);
    k_fuse<6><<<eg, eb, 0, stream>>>(c, (const f4*)y, ys, (const f4*)rec, act, kb, inputs, iw, tau, bias);
    k_gemm<<<gg, gb, 0, stream>>>(c, (const float*)act, W, rec);
    k_err<<<eg, eb, 0, stream>>>(c, (const f4*)y, (const f4*)ys, (const f4*)rec, kb, inputs, iw, tau);
    k_ctrl<<<1, 1, 0, stream>>>(c);
    k_yupd<<<eg, eb, 0, stream>>>(c, y, (const f4*)ys);
  }
}

// Round 2
// 1377.600 us; speedup vs baseline: 2.6124x; 2.6124x over previous
//
#include <hip/hip_runtime.h>
#include <math.h>

// CTRNN + adaptive DOPRI5 (B=2048, N=1024). Round 2: fp16 MFMA GEMM with
// fully fused stage epilogues; 8 dispatches per step; ping-pong y buffers
// and rotating act buffers selected via Ctl indices (no per-step copies).

typedef float f4 __attribute__((ext_vector_type(4)));
typedef float f32x4 __attribute__((ext_vector_type(4)));
typedef _Float16 half8v __attribute__((ext_vector_type(8)));
typedef _Float16 half4v __attribute__((ext_vector_type(4)));

#define AS1 __attribute__((address_space(1)))
#define AS3 __attribute__((address_space(3)))

#define BB 2048
#define NNU 1024
#define TOT ((size_t)BB * NNU)
#define NV (BB * NNU / 4)
#define COLMASK (NNU / 4 - 1)

#define E1c (71.0f / 57600.0f)
#define E3c (-71.0f / 16695.0f)
#define E4c (71.0f / 1920.0f)
#define E5c (-17253.0f / 339200.0f)
#define E6c (22.0f / 525.0f)
#define E7c (-1.0f / 40.0f)

struct Ctl {
  double sum;
  float t, dt;
  int ysel, a1;
};

__global__ void k_prep(const f4* __restrict__ W, half4v* __restrict__ Wh) {
  int i = blockIdx.x * blockDim.x + threadIdx.x;  // 0..262143
  f4 w = W[i];
  half4v o;
#pragma unroll
  for (int j = 0; j < 4; ++j) o[j] = (_Float16)w[j];
  Wh[i] = o;
}

__global__ void k_init(const f4* __restrict__ prev, const f4* __restrict__ bias,
                       f4* __restrict__ y, half4v* __restrict__ act1, Ctl* c) {
  int i = blockIdx.x * blockDim.x + threadIdx.x;
  f4 v = prev[i];
  y[i] = v;
  f4 b = bias[i & COLMASK];
  half4v a;
#pragma unroll
  for (int j = 0; j < 4; ++j) a[j] = (_Float16)tanhf(v[j] + b[j]);
  act1[i] = a;
  if (i == 0) { c->t = 0.0f; c->dt = 0.1f; c->sum = 0.0; c->ysel = 0; c->a1 = 0; }
}

// GEMM (rec = act * W^T) + fused DOPRI5 stage-S epilogue.
// Tile: 128x64, BK=32 fp16, 256 threads = 4 waves (2x2), wave tile 64x32.
template <int S>
__global__ __launch_bounds__(256) void k_stage(
    Ctl* __restrict__ c, const _Float16* __restrict__ Wh,
    float* __restrict__ yb0, float* __restrict__ yb1,
    _Float16* __restrict__ A0, _Float16* __restrict__ A1, _Float16* __restrict__ A2,
    float* __restrict__ kb,
    const float* __restrict__ inp, const float* __restrict__ iw,
    const float* __restrict__ tau, const float* __restrict__ bias) {
  float t = c->t;
  if (t >= 1.0f - 1e-7f) return;
  const float h = fminf(c->dt, 1.0f - t);
  int ysel = c->ysel & 1, a1 = c->a1;
  const float* y = ysel ? yb1 : yb0;
  float* ys = ysel ? yb0 : yb1;
  _Float16* AB[3] = {A0, A1, A2};
  int s0 = a1 + 1; if (s0 >= 3) s0 -= 3;
  int s1 = a1 + 2; if (s1 >= 3) s1 -= 3;
  const _Float16* Ain = (S == 1) ? AB[a1] : AB[((S - 1) & 1) ? s1 : s0];
  _Float16* Aout = AB[(S & 1) ? s1 : s0];

  __shared__ _Float16 As[128 * 32];
  __shared__ _Float16 Bs[64 * 32];

  const int tid = (int)threadIdx.x;
  const int lane = tid & 63, wv = tid >> 6;
  const int wr = wv >> 1, wc = wv & 1;
  const int lr = lane & 15, lk = lane >> 4;
  const int rowBase = blockIdx.x * 128, colBase = blockIdx.y * 64;

  f32x4 acc[4][2] = {};

  const int arow0 = tid >> 2, aseg = tid & 3;
  const int arow1 = 64 + (tid >> 2);
  const int brow = tid >> 2, bseg = tid & 3;
  const int sw0 = aseg ^ (arow0 & 3);   // seg-XOR swizzle (pre-swizzled source)
  const int sw1 = aseg ^ (arow1 & 3);
  const int swb = bseg ^ (brow & 3);

  for (int k0 = 0; k0 < NNU; k0 += 32) {
    if (k0) __syncthreads();
    __builtin_amdgcn_global_load_lds(
        (const AS1 void*)(Ain + (size_t)(rowBase + arow0) * NNU + k0 + sw0 * 8),
        (AS3 void*)(As + tid * 8), 16, 0, 0);
    __builtin_amdgcn_global_load_lds(
        (const AS1 void*)(Ain + (size_t)(rowBase + arow1) * NNU + k0 + sw1 * 8),
        (AS3 void*)(As + (256 + tid) * 8), 16, 0, 0);
    __builtin_amdgcn_global_load_lds(
        (const AS1 void*)(Wh + (size_t)(colBase + brow) * NNU + k0 + swb * 8),
        (AS3 void*)(Bs + tid * 8), 16, 0, 0);
    __syncthreads();

    half8v af[4], bf[2];
#pragma unroll
    for (int m = 0; m < 4; ++m) {
      int r = wr * 64 + m * 16 + lr;
      af[m] = *(const half8v*)(As + r * 32 + (lk ^ (r & 3)) * 8);
    }
#pragma unroll
    for (int n = 0; n < 2; ++n) {
      int r = wc * 32 + n * 16 + lr;
      bf[n] = *(const half8v*)(Bs + r * 32 + (lk ^ (r & 3)) * 8);
    }
#pragma unroll
    for (int m = 0; m < 4; ++m)
#pragma unroll
      for (int n = 0; n < 2; ++n)
        acc[m][n] = __builtin_amdgcn_mfma_f32_16x16x32_f16(af[m], bf[n], acc[m][n], 0, 0, 0);
  }

  float local = 0.0f;
#pragma unroll
  for (int m = 0; m < 4; ++m) {
#pragma unroll
    for (int j = 0; j < 4; ++j) {
      int b = rowBase + wr * 64 + m * 16 + lk * 4 + j;
      size_t rowo = (size_t)b * NNU;
#pragma unroll
      for (int n = 0; n < 2; ++n) {
        int i = colBase + wc * 32 + n * 16 + lr;
        size_t off = rowo + i;
        float rec = acc[m][n][j];
        float yv = y[off];
        float ysv = (S == 1) ? yv : ys[off];
        float itau = 1.0f / tau[i];
        float ks = itau * (rec - ysv + inp[off] * iw[i]);
        if constexpr (S <= 6) kb[(size_t)(S - 1) * TOT + off] = ks;
        if constexpr (S <= 6) {
          float nys;
          if constexpr (S == 1) {
            nys = yv + h * (0.2f * ks);
          } else if constexpr (S == 2) {
            float k1 = kb[off];
            nys = yv + h * ((3.0f / 40.0f) * k1 + (9.0f / 40.0f) * ks);
          } else if constexpr (S == 3) {
            float k1 = kb[off], k2 = kb[TOT + off];
            nys = yv + h * ((44.0f / 45.0f) * k1 + (-56.0f / 15.0f) * k2 + (32.0f / 9.0f) * ks);
          } else if constexpr (S == 4) {
            float k1 = kb[off], k2 = kb[TOT + off], k3 = kb[2 * TOT + off];
            nys = yv + h * ((19372.0f / 6561.0f) * k1 + (-25360.0f / 2187.0f) * k2 +
                            (64448.0f / 6561.0f) * k3 + (-212.0f / 729.0f) * ks);
          } else if constexpr (S == 5) {
            float k1 = kb[off], k2 = kb[TOT + off], k3 = kb[2 * TOT + off], k4 = kb[3 * TOT + off];
            nys = yv + h * ((9017.0f / 3168.0f) * k1 + (-355.0f / 33.0f) * k2 +
                            (46732.0f / 5247.0f) * k3 + (49.0f / 176.0f) * k4 +
                            (-5103.0f / 18656.0f) * ks);
          } else {  // S == 6 -> y5
            float k1 = kb[off], k3 = kb[2 * TOT + off], k4 = kb[3 * TOT + off], k5 = kb[4 * TOT + off];
            nys = yv + h * ((35.0f / 384.0f) * k1 + (500.0f / 1113.0f) * k3 +
                            (125.0f / 192.0f) * k4 + (-2187.0f / 6784.0f) * k5 +
                            (11.0f / 84.0f) * ks);
          }
          ys[off] = nys;
          Aout[off] = (_Float16)tanhf(nys + bias[i]);
        } else {  // S == 7: error norm
          float k1 = kb[off], k3 = kb[2 * TOT + off], k4 = kb[3 * TOT + off];
          float k5 = kb[4 * TOT + off], k6 = kb[5 * TOT + off];
          float err = h * (E1c * k1 + E3c * k3 + E4c * k4 + E5c * k5 + E6c * k6 + E7c * ks);
          float sc = 1e-6f + 1e-3f * fmaxf(fabsf(yv), fabsf(ysv));
          float r = err / sc;
          local += r * r;
        }
      }
    }
  }

  if constexpr (S == 7) {
#pragma unroll
    for (int o = 32; o > 0; o >>= 1) local += __shfl_down(local, o, 64);
    __shared__ float wsum[4];
    if (lane == 0) wsum[wv] = local;
    __syncthreads();
    if (tid == 0)
      atomicAdd(&c->sum, (double)(wsum[0] + wsum[1] + wsum[2] + wsum[3]));
  }
}

__global__ void k_ctrl(Ctl* c) {
  float t = c->t;
  if (t >= 1.0f - 1e-7f) return;
  float h = fminf(c->dt, 1.0f - t);
  double s = c->sum;
  c->sum = 0.0;
  float enorm = fmaxf(sqrtf((float)(s / (double)TOT)), 1e-10f);
  if (enorm <= 1.0f) {
    c->t = t + h;
    c->ysel ^= 1;
    int a = c->a1 + 1;
    c->a1 = (a >= 3) ? a - 3 : a;
  }
  float factor = fminf(fmaxf(0.9f * powf(enorm, -0.2f), 0.2f), 5.0f);
  c->dt = c->dt * factor;
}

__global__ void k_final(const Ctl* __restrict__ c, f4* __restrict__ y0,
                        const f4* __restrict__ y1) {
  if (!(c->ysel & 1)) return;
  int i = blockIdx.x * blockDim.x + threadIdx.x;
  y0[i] = y1[i];
}

extern "C" void kernel_launch(void* const* d_in, const int* in_sizes, int n_in,
                              void* d_out, int out_size, void* d_ws, size_t ws_size,
                              hipStream_t stream) {
  const float* inp = (const float*)d_in[0];
  const f4* prev = (const f4*)d_in[1];
  const float* tau = (const float*)d_in[2];
  const f4* W = (const f4*)d_in[3];
  const float* iw = (const float*)d_in[4];
  const float* bias = (const float*)d_in[5];
  float* y0 = (float*)d_out;

  char* ws = (char*)d_ws;
  const size_t MB = 1024 * 1024;
  Ctl* c = (Ctl*)ws;
  _Float16* Wh = (_Float16*)(ws + 256);             // 2 MB
  _Float16* A0 = (_Float16*)(ws + 256 + 2 * MB);    // 4 MB each
  _Float16* A1 = (_Float16*)(ws + 256 + 6 * MB);
  _Float16* A2 = (_Float16*)(ws + 256 + 10 * MB);
  float* kb = (float*)(ws + 256 + 14 * MB);         // 48 MB (k1..k6)
  float* y1 = (float*)(ws + 256 + 62 * MB);         // 8 MB

  k_prep<<<1024, 256, 0, stream>>>(W, (half4v*)Wh);
  k_init<<<2048, 256, 0, stream>>>(prev, (const f4*)bias, (f4*)y0, (half4v*)A0, c);

  dim3 gg(BB / 128, NNU / 64), gb(256);
  for (int s = 0; s < 40; ++s) {
    k_stage<1><<<gg, gb, 0, stream>>>(c, Wh, y0, y1, A0, A1, A2, kb, inp, iw, tau, bias);
    k_stage<2><<<gg, gb, 0, stream>>>(c, Wh, y0, y1, A0, A1, A2, kb, inp, iw, tau, bias);
    k_stage<3><<<gg, gb, 0, stream>>>(c, Wh, y0, y1, A0, A1, A2, kb, inp, iw, tau, bias);
    k_stage<4><<<gg, gb, 0, stream>>>(c, Wh, y0, y1, A0, A1, A2, kb, inp, iw, tau, bias);
    k_stage<5><<<gg, gb, 0, stream>>>(c, Wh, y0, y1, A0, A1, A2, kb, inp, iw, tau, bias);
    k_stage<6><<<gg, gb, 0, stream>>>(c, Wh, y0, y1, A0, A1, A2, kb, inp, iw, tau, bias);
    k_stage<7><<<gg, gb, 0, stream>>>(c, Wh, y0, y1, A0, A1, A2, kb, inp, iw, tau, bias);
    k_ctrl<<<1, 1, 0, stream>>>(c);
  }
  k_final<<<2048, 256, 0, stream>>>(c, (f4*)y0, (const f4*)y1);
}